// Round 1
// baseline (361.690 us; speedup 1.0000x reference)
//
#include <hip/hip_runtime.h>

// SSP transform: out[b,n] = 1/513 + sum_k A[b,k]*Bt[n,k]
//   A[b,j]=cos(x_b*phi_j), A[b,256+j]=sin(x_b*phi_j)
//   Bt[n,j]=(2/513)cos(2pi(j+1)n/513), Bt[n,256+j]=-(2/513)sin(2pi(j+1)n/513)
// Strategy: bf16 MFMA GEMM M=131072 N=513(pad 544) K=512.
//   genB: build swizzled Bt (bf16) in d_ws (0.55 MB), integer-exact angle reduction.
//   ssp_main: 1024 blocks x 4 waves; wave = 32 rows; A-slab in regs (sincos),
//   Bt double-buffered in LDS via global_load_lds (pre-swizzled global layout).

#define DIMN 513
#define KDIM 512
#define NPAD 544
#define NPAIRS 17          // 544 cols / 32 per pair-tile
#define BM 128             // rows per block (4 waves * 32)
#define INV_N (1.0f / 513.0f)

typedef __attribute__((ext_vector_type(8))) short short8;   // 8 bf16 = 4 VGPRs
typedef __attribute__((ext_vector_type(4))) float f32x4;    // MFMA acc
typedef __attribute__((ext_vector_type(4))) float f4;

__device__ __forceinline__ short bf16r(float f) {
  // round-to-nearest-even f32 -> bf16 (inputs are finite, no NaN handling)
  unsigned u = __float_as_uint(f);
  u += 0x7FFFu + ((u >> 16) & 1u);
  return (short)(u >> 16);
}

// ---------------- genB: constant matrix, swizzled for LDS staging --------------
// Logical element (n,k) -> byte (within 32-row chunk) w = (n&31)*1024 + k*2,
// stored at (n>>5)*32768 + (w ^ ((n&7)<<4)). The main kernel copies chunks
// linearly to LDS and reads with the same XOR -> bank-conflict-free ds_read_b128.
__global__ void ssp_genB(unsigned short* __restrict__ bt) {
  int idx = blockIdx.x * 256 + threadIdx.x;   // 544*512 = 278528 elements
  int n = idx >> 9;                           // 0..543 (rows >=513 are pad)
  int k = idx & 511;
  int j = k & 255;
  unsigned prod = (unsigned)(j + 1) * (unsigned)n;   // exact
  unsigned m = prod % 513u;                          // exact angle reduction
  float ang = (float)m * (6.283185307179586f / 513.0f);
  float s, c;
  __sincosf(ang, &s, &c);
  float v = (k < 256) ? c * (2.0f / 513.0f) : -(s * (2.0f / 513.0f));
  unsigned chunk = (unsigned)n >> 5;
  unsigned w = ((unsigned)(n & 31) << 10) + ((unsigned)k << 1);
  unsigned phys = (chunk << 15) + (w ^ ((unsigned)(n & 7) << 4));
  bt[phys >> 1] = (unsigned short)bf16r(v);
}

// ---------------- main fused kernel -------------------------------------------
__global__ __launch_bounds__(256, 2) void ssp_main(
    const float* __restrict__ x, const float* __restrict__ phis,
    const unsigned short* __restrict__ bt, float* __restrict__ out) {
  __shared__ __align__(16) unsigned char lds[65536];   // 2 x 32KB Bt tiles
  const int tid = threadIdx.x;
  const int w = tid >> 6;          // wave 0..3
  const int lane = tid & 63;
  const int r = lane & 15;
  const int q = lane >> 4;
  const long rowW = (long)blockIdx.x * BM + w * 32;

  // ---- Phase 1: build A fragments in registers ----
  // afrag[f][t] elem e = A[rowW + f*16 + r][k = 32t + 8q + e] as bf16
  // t<8 -> cos part (j = 32t+8q+e), t>=8 -> sin part (same j set)
  short8 afrag[2][16];
  const float x0 = x[rowW + r];
  const float x1 = x[rowW + 16 + r];
#pragma unroll
  for (int u = 0; u < 8; ++u) {
    const f4* pp4 = (const f4*)(phis + 32 * u + 8 * q);
    f4 plo = pp4[0];
    f4 phi4 = pp4[1];
#pragma unroll
    for (int e = 0; e < 8; ++e) {
      float ph = (e < 4) ? plo[e] : phi4[e - 4];
      float s0, c0, s1, c1;
      __sincosf(x0 * ph, &s0, &c0);
      __sincosf(x1 * ph, &s1, &c1);
      afrag[0][u][e]     = bf16r(c0);
      afrag[0][u + 8][e] = bf16r(s0);
      afrag[1][u][e]     = bf16r(c1);
      afrag[1][u + 8][e] = bf16r(s1);
    }
  }

  const unsigned char* btb = (const unsigned char*)bt;

  // ---- prologue: stage chunk 0 into buffer 0 (32KB, 8 x 1KB per wave) ----
  {
    const unsigned char* src = btb + (w * 8) * 1024 + lane * 16;
    unsigned char* dst = &lds[(w * 8) * 1024];
#pragma unroll
    for (int i = 0; i < 8; ++i)
      __builtin_amdgcn_global_load_lds(
          (const __attribute__((address_space(1))) unsigned int*)(src + i * 1024),
          (__attribute__((address_space(3))) unsigned int*)(dst + i * 1024),
          16, 0, 0);
  }
  __syncthreads();   // drains vmcnt before first compute

  // hoisted swizzled ds_read base offsets (per nf, per k-step parity)
  const int sw  = (r & 7) << 4;
  const int be0 = (r << 10)        + ((q << 4) ^ sw);
  const int bo0 = (r << 10)        + ((64 | (q << 4)) ^ sw);
  const int be1 = ((16 + r) << 10) + ((q << 4) ^ sw);
  const int bo1 = ((16 + r) << 10) + ((64 | (q << 4)) ^ sw);

  const long outRowBase = rowW + 4 * q;

  for (int p = 0; p < NPAIRS; ++p) {
    const int buf = (p & 1) * 32768;

    // stage next pair-tile into the other buffer (2-phase pipeline)
    if (p + 1 < NPAIRS) {
      const unsigned char* src = btb + (p + 1) * 32768 + (w * 8) * 1024 + lane * 16;
      unsigned char* dst = &lds[((p + 1) & 1) * 32768 + (w * 8) * 1024];
#pragma unroll
      for (int i = 0; i < 8; ++i)
        __builtin_amdgcn_global_load_lds(
            (const __attribute__((address_space(1))) unsigned int*)(src + i * 1024),
            (__attribute__((address_space(3))) unsigned int*)(dst + i * 1024),
            16, 0, 0);
    }

    // ---- K loop: 16 k-steps, 4 independent MFMA chains ----
    f32x4 acc00 = {0.f, 0.f, 0.f, 0.f};
    f32x4 acc01 = {0.f, 0.f, 0.f, 0.f};
    f32x4 acc10 = {0.f, 0.f, 0.f, 0.f};
    f32x4 acc11 = {0.f, 0.f, 0.f, 0.f};
#pragma unroll
    for (int t = 0; t < 16; ++t) {
      const int o0 = buf + ((t & 1) ? bo0 : be0) + (t >> 1) * 128;
      const int o1 = buf + ((t & 1) ? bo1 : be1) + (t >> 1) * 128;
      short8 b0 = *(const short8*)&lds[o0];
      short8 b1 = *(const short8*)&lds[o1];
      acc00 = __builtin_amdgcn_mfma_f32_16x16x32_bf16(afrag[0][t], b0, acc00, 0, 0, 0);
      acc10 = __builtin_amdgcn_mfma_f32_16x16x32_bf16(afrag[1][t], b0, acc10, 0, 0, 0);
      acc01 = __builtin_amdgcn_mfma_f32_16x16x32_bf16(afrag[0][t], b1, acc01, 0, 0, 0);
      acc11 = __builtin_amdgcn_mfma_f32_16x16x32_bf16(afrag[1][t], b1, acc11, 0, 0, 0);
    }

    // ---- epilogue: C/D layout col = lane&15, row = 4q + reg ----
    const int col0 = p * 32 + r;
#pragma unroll
    for (int rr = 0; rr < 4; ++rr) {
      const long ro0 = (outRowBase + rr) * DIMN;
      const long ro1 = (outRowBase + 16 + rr) * DIMN;
      if (col0 < DIMN) {
        out[ro0 + col0] = acc00[rr] + INV_N;
        out[ro1 + col0] = acc10[rr] + INV_N;
      }
      if (col0 + 16 < DIMN) {
        out[ro0 + col0 + 16] = acc01[rr] + INV_N;
        out[ro1 + col0 + 16] = acc11[rr] + INV_N;
      }
    }

    __syncthreads();   // staged loads landed + all waves done with buf
  }
}

extern "C" void kernel_launch(void* const* d_in, const int* in_sizes, int n_in,
                              void* d_out, int out_size, void* d_ws, size_t ws_size,
                              hipStream_t stream) {
  const float* x = (const float*)d_in[0];          // (131072,) inputs
  const float* phis = (const float*)d_in[1];       // (256,)
  float* out = (float*)d_out;                      // (131072, 513) f32
  unsigned short* bt = (unsigned short*)d_ws;      // 544*512 bf16 = 557056 B

  ssp_genB<<<dim3(NPAD * KDIM / 256), dim3(256), 0, stream>>>(bt);
  ssp_main<<<dim3(131072 / BM), dim3(256), 0, stream>>>(x, phis, bt, out);
}

// Round 10
// 354.189 us; speedup vs baseline: 1.0212x; 1.0212x over previous
//
#include <hip/hip_runtime.h>

// SSP transform: out[b,n] = 1/513 + sum_k A[b,k]*Bt[n,k]
//   A[b,j]=cos(x_b*phi_j), A[b,256+j]=sin(x_b*phi_j)
//   Bt[n,j]=(2/513)cos(2pi(j+1)n/513), Bt[n,256+j]=-(2/513)sin(2pi(j+1)n/513)
// bf16 MFMA GEMM M=131072 N=513(pad 544) K=512.
// R2 changes vs R1 (361.7 us):
//  - operand-swapped MFMA: D layout col=batch,row=n -> 4x float4 (align-4)
//    coalesced stores/iter instead of 16 branchy scalar dword stores.
//  - counted s_waitcnt vmcnt(4) + raw s_barrier instead of __syncthreads():
//    output stores stay in flight across the barrier (T4 idiom); only the
//    Bt prefetch is guaranteed landed. Removes store-drain serialization.
//  - tile-0 prefetch issued before the sincos phase (latency hidden).
// R3-R10 = R2 resubmitted verbatim (R2-R9 benches were GPUAcquisitionTimeout).

#define DIMN 513
#define KDIM 512
#define NPAD 544
#define NPAIRS 17
#define BM 128
#define INV_N (1.0f / 513.0f)

typedef __attribute__((ext_vector_type(8))) short short8;   // 8 bf16
typedef __attribute__((ext_vector_type(4))) float f32x4;
typedef __attribute__((ext_vector_type(4))) float f4;
typedef __attribute__((ext_vector_type(4), aligned(4))) float f4u; // unaligned-ok store

__device__ __forceinline__ short bf16r(float f) {
  unsigned u = __float_as_uint(f);
  u += 0x7FFFu + ((u >> 16) & 1u);
  return (short)(u >> 16);
}

// ---------------- genB: constant matrix, swizzled for LDS staging --------------
// Logical (n,k) -> within-32-row-chunk byte w = (n&31)*1024 + k*2,
// stored at (n>>5)*32768 + (w ^ ((n&7)<<4)). Main kernel copies chunks linearly
// to LDS (global_load_lds) and reads with the same XOR -> conflict-free b128.
__global__ void ssp_genB(unsigned short* __restrict__ bt) {
  int idx = blockIdx.x * 256 + threadIdx.x;   // 544*512 = 278528
  int n = idx >> 9;
  int k = idx & 511;
  int j = k & 255;
  unsigned prod = (unsigned)(j + 1) * (unsigned)n;
  unsigned m = prod % 513u;                   // exact angle reduction
  float ang = (float)m * (6.283185307179586f / 513.0f);
  float s, c;
  __sincosf(ang, &s, &c);
  float v = (k < 256) ? c * (2.0f / 513.0f) : -(s * (2.0f / 513.0f));
  unsigned chunk = (unsigned)n >> 5;
  unsigned w = ((unsigned)(n & 31) << 10) + ((unsigned)k << 1);
  unsigned phys = (chunk << 15) + (w ^ ((unsigned)(n & 7) << 4));
  bt[phys >> 1] = (unsigned short)bf16r(v);
}

// ---------------- main fused kernel -------------------------------------------
__global__ __launch_bounds__(256, 2) void ssp_main(
    const float* __restrict__ x, const float* __restrict__ phis,
    const unsigned short* __restrict__ bt, float* __restrict__ out) {
  __shared__ __align__(16) unsigned char lds[65536];   // 2 x 32KB Bt tiles
  const int tid = threadIdx.x;
  const int w = tid >> 6;
  const int lane = tid & 63;
  const int r = lane & 15;
  const int q = lane >> 4;
  const long rowW = (long)blockIdx.x * BM + w * 32;

  const unsigned char* btb = (const unsigned char*)bt;

  // ---- issue tile-0 prefetch first; its latency hides under sincos ----
  {
    const unsigned char* src = btb + (w * 8) * 1024 + lane * 16;
    unsigned char* dst = &lds[(w * 8) * 1024];
#pragma unroll
    for (int i = 0; i < 8; ++i)
      __builtin_amdgcn_global_load_lds(
          (const __attribute__((address_space(1))) unsigned int*)(src + i * 1024),
          (__attribute__((address_space(3))) unsigned int*)(dst + i * 1024),
          16, 0, 0);
  }

  // ---- Phase 1: A fragments in registers ----
  // afrag[f][t] elem e = A[rowW + f*16 + r][k = 32t + 8q + e] (bf16)
  short8 afrag[2][16];
  const float x0 = x[rowW + r];
  const float x1 = x[rowW + 16 + r];
#pragma unroll
  for (int u = 0; u < 8; ++u) {
    const f4* pp4 = (const f4*)(phis + 32 * u + 8 * q);
    f4 plo = pp4[0];
    f4 phi4 = pp4[1];
#pragma unroll
    for (int e = 0; e < 8; ++e) {
      float ph = (e < 4) ? plo[e] : phi4[e - 4];
      float s0, c0, s1, c1;
      __sincosf(x0 * ph, &s0, &c0);
      __sincosf(x1 * ph, &s1, &c1);
      afrag[0][u][e]     = bf16r(c0);
      afrag[0][u + 8][e] = bf16r(s0);
      afrag[1][u][e]     = bf16r(c1);
      afrag[1][u + 8][e] = bf16r(s1);
    }
  }

  // prologue drain: tile-0 (and x/phis) landed, everyone synced
  asm volatile("s_waitcnt vmcnt(0) lgkmcnt(0)" ::: "memory");
  __builtin_amdgcn_s_barrier();

  // swizzled ds_read base offsets
  const int sw  = (r & 7) << 4;
  const int be0 = (r << 10)        + ((q << 4) ^ sw);
  const int bo0 = (r << 10)        + ((64 | (q << 4)) ^ sw);
  const int be1 = ((16 + r) << 10) + ((q << 4) ^ sw);
  const int bo1 = ((16 + r) << 10) + ((64 | (q << 4)) ^ sw);

  float* const o0 = out + (rowW + r) * DIMN;        // batch row for afrag[0]
  float* const o1 = out + (rowW + 16 + r) * DIMN;   // batch row for afrag[1]

  for (int p = 0; p < NPAIRS; ++p) {
    const int buf = (p & 1) * 32768;

    // (A) prefetch next tile (8 vmem loads)
    if (p + 1 < NPAIRS) {
      const unsigned char* src = btb + (p + 1) * 32768 + (w * 8) * 1024 + lane * 16;
      unsigned char* dst = &lds[((p + 1) & 1) * 32768 + (w * 8) * 1024];
#pragma unroll
      for (int i = 0; i < 8; ++i)
        __builtin_amdgcn_global_load_lds(
            (const __attribute__((address_space(1))) unsigned int*)(src + i * 1024),
            (__attribute__((address_space(3))) unsigned int*)(dst + i * 1024),
            16, 0, 0);
    }
    __builtin_amdgcn_sched_barrier(0);   // pin loads before K-loop/stores

    // (B) K loop: 16 k-steps; operand-swapped MFMA -> D[col=batch,row=n]
    f32x4 acc00 = {0.f, 0.f, 0.f, 0.f};
    f32x4 acc01 = {0.f, 0.f, 0.f, 0.f};
    f32x4 acc10 = {0.f, 0.f, 0.f, 0.f};
    f32x4 acc11 = {0.f, 0.f, 0.f, 0.f};
#pragma unroll
    for (int t = 0; t < 16; ++t) {
      const int o0b = buf + ((t & 1) ? bo0 : be0) + (t >> 1) * 128;
      const int o1b = buf + ((t & 1) ? bo1 : be1) + (t >> 1) * 128;
      short8 b0 = *(const short8*)&lds[o0b];
      short8 b1 = *(const short8*)&lds[o1b];
      acc00 = __builtin_amdgcn_mfma_f32_16x16x32_bf16(b0, afrag[0][t], acc00, 0, 0, 0);
      acc10 = __builtin_amdgcn_mfma_f32_16x16x32_bf16(b0, afrag[1][t], acc10, 0, 0, 0);
      acc01 = __builtin_amdgcn_mfma_f32_16x16x32_bf16(b1, afrag[0][t], acc01, 0, 0, 0);
      acc11 = __builtin_amdgcn_mfma_f32_16x16x32_bf16(b1, afrag[1][t], acc11, 0, 0, 0);
    }

    // (C) epilogue: lane holds n = p*32 + (0|16) + 4q + rr for batch col r
    const int nb = p * 32 + 4 * q;
    if (p < 16) {
      *(f4u*)(o0 + nb)      = acc00 + INV_N;
      *(f4u*)(o0 + nb + 16) = acc01 + INV_N;
      *(f4u*)(o1 + nb)      = acc10 + INV_N;
      *(f4u*)(o1 + nb + 16) = acc11 + INV_N;
    } else {
      // n range 512..543; only n==512 valid (q==0, rr==0 of low tile)
      if (q == 0) {
        o0[512] = acc00[0] + INV_N;
        o1[512] = acc10[0] + INV_N;
      }
    }
    __builtin_amdgcn_sched_barrier(0);

    // (D) counted drain: 4 newest vmem ops are this iter's stores; anything
    // older (the 8 prefetch loads) is forced complete. Stores stay in flight.
    asm volatile("s_waitcnt vmcnt(4)" ::: "memory");
    // (E) all waves' prefetches landed; buf[cur] fully consumed (ds reads
    // retired before MFMA use) -> safe to swap buffers
    __builtin_amdgcn_s_barrier();
  }
}

extern "C" void kernel_launch(void* const* d_in, const int* in_sizes, int n_in,
                              void* d_out, int out_size, void* d_ws, size_t ws_size,
                              hipStream_t stream) {
  const float* x = (const float*)d_in[0];
  const float* phis = (const float*)d_in[1];
  float* out = (float*)d_out;
  unsigned short* bt = (unsigned short*)d_ws;   // 544*512 bf16 = 557056 B

  ssp_genB<<<dim3(NPAD * KDIM / 256), dim3(256), 0, stream>>>(bt);
  ssp_main<<<dim3(131072 / BM), dim3(256), 0, stream>>>(x, phis, bt, out);
}